// Round 15
// baseline (238.760 us; speedup 1.0000x reference)
//
#include <hip/hip_runtime.h>
#include <cstdint>

typedef _Float16 half4 __attribute__((ext_vector_type(4)));
typedef _Float16 half8 __attribute__((ext_vector_type(8)));
typedef _Float16 half16 __attribute__((ext_vector_type(16)));
typedef float f32x4 __attribute__((ext_vector_type(4)));
typedef float f32x16 __attribute__((ext_vector_type(16)));

#define L2E 1.44269504088896340736f

__device__ __forceinline__ void gl16(const void* g, void* l) {
  __builtin_amdgcn_global_load_lds(
      (const __attribute__((address_space(1))) void*)g,
      (__attribute__((address_space(3))) void*)l, 16, 0, 0);
}

__device__ __forceinline__ uint32_t pk2(float a, float b) {
  return __builtin_bit_cast(uint32_t, __builtin_amdgcn_cvt_pkrtz(a, b));
}

__device__ __forceinline__ void plswap(uint32_t& x, uint32_t& y) {
  auto r = __builtin_amdgcn_permlane32_swap((int)x, (int)y, false, false);
  x = (uint32_t)r[0];
  y = (uint32_t)r[1];
}

__device__ __forceinline__ f32x16 zero16() {
  f32x16 z;
  #pragma unroll
  for (int r = 0; r < 16; ++r) z[r] = 0.0f;
  return z;
}

// ---------------------------------------------------------------------------
// Merged prologue: activation fp32->fp16 convert (ids 0..12287) + weight
// transpose/convert (ids 12288..22527). Block (32,8) = 256 threads.
// ---------------------------------------------------------------------------
__global__ __launch_bounds__(256) void prep_all(
    const float* __restrict__ q, const float* __restrict__ k, const float* __restrict__ v,
    const float* __restrict__ Wq, const float* __restrict__ Wk,
    const float* __restrict__ Wv, const float* __restrict__ Wo,
    _Float16* __restrict__ qh, _Float16* __restrict__ kh, _Float16* __restrict__ vh,
    _Float16* __restrict__ WqkvT, _Float16* __restrict__ WoT)
{
  int id = blockIdx.x;
  const int tid = threadIdx.y * 32 + threadIdx.x;
  if (id < 12288) {
    const int z = id >> 12;
    const int x = id & 4095;
    const float* src = (z == 0) ? q : (z == 1 ? k : v);
    _Float16* dst    = (z == 0) ? qh : (z == 1 ? kh : vh);
    size_t i = ((size_t)x * 256 + tid) * 8;
    float4 a = *(const float4*)(src + i);
    float4 b = *(const float4*)(src + i + 4);
    half8 o;
    o[0] = (_Float16)a.x; o[1] = (_Float16)a.y; o[2] = (_Float16)a.z; o[3] = (_Float16)a.w;
    o[4] = (_Float16)b.x; o[5] = (_Float16)b.y; o[6] = (_Float16)b.z; o[7] = (_Float16)b.w;
    *(half8*)(dst + i) = o;
    return;
  }
  id -= 12288;
  const float* src;
  _Float16* dst;
  int N, tx, ty;
  if (id < 4096)      { src = Wq; dst = WqkvT;                        N = 2048; tx = id & 63; ty = id >> 6; }
  else if (id < 5120) { id -= 4096; src = Wk; dst = WqkvT + (size_t)2048 * 2048; N = 512; tx = id & 15; ty = id >> 4; }
  else if (id < 6144) { id -= 5120; src = Wv; dst = WqkvT + (size_t)2560 * 2048; N = 512; tx = id & 15; ty = id >> 4; }
  else                { id -= 6144; src = Wo; dst = WoT;              N = 2048; tx = id & 63; ty = id >> 6; }
  const int n0 = tx * 32, k0 = ty * 32;
  __shared__ float t[32][33];
  #pragma unroll
  for (int i = 0; i < 4; ++i)
    t[threadIdx.y + i * 8][threadIdx.x] =
        src[(size_t)(k0 + threadIdx.y + i * 8) * N + n0 + threadIdx.x];
  __syncthreads();
  #pragma unroll
  for (int i = 0; i < 4; ++i)
    dst[(size_t)(n0 + threadIdx.y + i * 8) * 2048 + k0 + threadIdx.x] =
        (_Float16)t[threadIdx.x][threadIdx.y + i * 8];
}

// ---------------------------------------------------------------------------
// fp16 GEMM v9 (R14-proven, unchanged): BM=128, BN=128, BK=32, 512 thr /
// 8 waves, all-gl16 staging, 3-buffer LDS, counted vmcnt(2), raw s_barrier,
// XCD swizzle. MODE 0: QKV proj (grid 768), fused V^T epilogue.
// MODE 1: O proj (grid 512), fp32 out.
// ---------------------------------------------------------------------------
template<int MODE>
__global__ __launch_bounds__(512, 2) void gemm128(
    const _Float16* __restrict__ Aq, const _Float16* __restrict__ Ak, const _Float16* __restrict__ Av,
    const _Float16* __restrict__ Bt,
    const float* __restrict__ bias0, const float* __restrict__ bias1, const float* __restrict__ bias2,
    _Float16* __restrict__ Ch, float* __restrict__ Cf, _Float16* __restrict__ VTo)
{
  constexpr int K = 2048;
  constexpr int N = (MODE == 0) ? 3072 : 2048;
  constexpr int NB = N / 128;
  constexpr int G = 32 * NB;
  constexpr int BUF = 8192 + 8192;
  constexpr int TPAD = 136;

  const int wg = blockIdx.x;
  const int work = (wg & 7) * (G / 8) + (wg >> 3);
  const int m0 = (work / NB) * 128;
  const int n0 = (work % NB) * 128;

  const _Float16* A = Aq;
  if constexpr (MODE == 0) { if (n0 >= 2560) A = Av; else if (n0 >= 2048) A = Ak; }

  const int tid = threadIdx.x;
  const int lane = tid & 63;
  const int w = tid >> 6;
  const int wr = w >> 2;
  const int wc = w & 3;
  const int lo = lane & 15, hi = lane >> 4;

  __shared__ __align__(1024) char smem[3 * BUF];

  f32x4 acc[4][2];
  #pragma unroll
  for (int mt = 0; mt < 4; ++mt)
    #pragma unroll
    for (int nt = 0; nt < 2; ++nt)
      acc[mt][nt] = (f32x4){0.f, 0.f, 0.f, 0.f};

  const _Float16* pB = Bt + (size_t)(n0 + w * 16 + (lane >> 2)) * K + (lane & 3) * 8;
  const _Float16* pA = A  + (size_t)(m0 + w * 16 + (lane >> 2)) * K + (lane & 3) * 8;
  const int dstB = 8192 + w * 1024;
  const int dstA = w * 1024;

  #define STAGE(base)                                                         \
    do {                                                                      \
      gl16(pA, (base) + dstA);                                                \
      gl16(pB, (base) + dstB);                                                \
    } while (0)

  STAGE(smem);
  pA += 32; pB += 32;
  STAGE(smem + BUF);
  pA += 32; pB += 32;
  asm volatile("s_waitcnt vmcnt(2)" ::: "memory");
  __builtin_amdgcn_s_barrier();

  const int abase = (wr * 64 + lo) * 64 + hi * 16;
  const int bbase = 8192 + (wc * 32 + lo) * 64 + hi * 16;

  int c = 0;
  for (int t = 0; t < 64; ++t) {
    int c1 = c + 1; if (c1 == 3) c1 = 0;
    int c2 = c1 + 1; if (c2 == 3) c2 = 0;
    if (t < 62) {
      STAGE(smem + c2 * BUF);
      pA += 32; pB += 32;
    }

    const char* bc = smem + c * BUF;
    half8 af[4], bf[2];
    #pragma unroll
    for (int mt = 0; mt < 4; ++mt) af[mt] = *(const half8*)(bc + abase + mt * 1024);
    #pragma unroll
    for (int nt = 0; nt < 2; ++nt) bf[nt] = *(const half8*)(bc + bbase + nt * 1024);

    __builtin_amdgcn_s_setprio(1);
    #pragma unroll
    for (int mt = 0; mt < 4; ++mt)
      #pragma unroll
      for (int nt = 0; nt < 2; ++nt)
        acc[mt][nt] = __builtin_amdgcn_mfma_f32_16x16x32_f16(af[mt], bf[nt], acc[mt][nt], 0, 0, 0);
    __builtin_amdgcn_s_setprio(0);

    if (t < 62)       asm volatile("s_waitcnt vmcnt(2)" ::: "memory");
    else if (t == 62) asm volatile("s_waitcnt vmcnt(0)" ::: "memory");
    if (t < 63) __builtin_amdgcn_s_barrier();
    c = c1;
  }
  #undef STAGE

  const bool isV = (MODE == 0) && (n0 >= 2560);
  float* T = (float*)smem;
  const int tr = tid >> 4;
  const int sc = tid & 15;
  #pragma unroll
  for (int mp = 0; mp < 4; ++mp) {
    __syncthreads();
    #pragma unroll
    for (int nt = 0; nt < 2; ++nt)
      #pragma unroll
      for (int r = 0; r < 4; ++r)
        T[(wr * 16 + 4 * hi + r) * TPAD + wc * 32 + nt * 16 + lo] = acc[mp][nt][r];
    __syncthreads();
    if (isV) {
      const int cv = tid & 127;
      const int tg = tid >> 7;
      const int run = tg >> 1, hb = tg & 1;
      const int vd = n0 - 2560 + cv;
      const int hV = vd >> 6, dV = vd & 63;
      const float bias = bias2[vd];
      const int trow0 = run * 16 + hb * 8;
      const int tglob = m0 + run * 64 + mp * 16 + hb * 8;
      const int bb = tglob >> 11;
      const int tloc = tglob & 2047;
      half8 o;
      #pragma unroll
      for (int e = 0; e < 8; ++e)
        o[e] = (_Float16)(T[(trow0 + e) * TPAD + cv] + bias);
      *(half8*)(VTo + ((size_t)(bb * 8 + hV) * 64 + dV) * 2048 + tloc) = o;
    } else {
      const int grow = m0 + (tr >> 4) * 64 + mp * 16 + (tr & 15);
      const int gcol = n0 + sc * 8;
      const float* Trow = T + tr * TPAD + sc * 8;
      const float* bp = bias0;
      int cb = gcol;
      if constexpr (MODE == 0) {
        if (gcol >= 2048) { bp = bias1; cb = gcol - 2048; }
      }
      float4 v0 = ((const float4*)Trow)[0];
      float4 v1 = ((const float4*)Trow)[1];
      float4 b0 = ((const float4*)(bp + cb))[0];
      float4 b1 = ((const float4*)(bp + cb))[1];
      if constexpr (MODE == 0) {
        half8 o;
        o[0] = (_Float16)(v0.x + b0.x); o[1] = (_Float16)(v0.y + b0.y);
        o[2] = (_Float16)(v0.z + b0.z); o[3] = (_Float16)(v0.w + b0.w);
        o[4] = (_Float16)(v1.x + b1.x); o[5] = (_Float16)(v1.y + b1.y);
        o[6] = (_Float16)(v1.z + b1.z); o[7] = (_Float16)(v1.w + b1.w);
        *(half8*)(Ch + (size_t)grow * N + gcol) = o;
      } else {
        float* dstp = Cf + (size_t)grow * N + gcol;
        float4 o0 = {v0.x + b0.x, v0.y + b0.y, v0.z + b0.z, v0.w + b0.w};
        float4 o1 = {v1.x + b1.x, v1.y + b1.y, v1.z + b1.z, v1.w + b1.w};
        ((float4*)dstp)[0] = o0;
        ((float4*)dstp)[1] = o1;
      }
    }
  }
}

// ---------------------------------------------------------------------------
// Flash attention v6: GQA 2-q-heads-per-wave. Each wave computes TWO q-heads
// (grp pair 2*qp, 2*qp+1 of the same kv-head) against shared K/V fragments:
// kf[4] hoisted once per 32-key half -> 2 QK-MFMA chains; each vf read feeds
// 2 PV-MFMAs. ds_read:MFMA halves; per-wave MFMA ILP doubles; VALU:MFMA
// unchanged. Grid 512 (2 blocks/CU, waves from different blocks ->
// uncorrelated phases). K/V staging, no-max softmax, exp2-domain Q prescale
// identical to the R6-proven v4.
// ---------------------------------------------------------------------------
__global__ __launch_bounds__(256, 2) void attn_fwd6(
    const _Float16* __restrict__ QKV, const _Float16* __restrict__ VT,
    _Float16* __restrict__ AO)
{
  // 512 blocks: (b,h) 16 x qp 2 x qt 16, XCD-chunked
  const int wg = blockIdx.x;
  const int work = (wg & 7) * 64 + (wg >> 3);
  const int bh = work >> 5;
  const int b = bh >> 3, h = bh & 7;
  const int rem = work & 31;
  const int qp = rem >> 4;            // q-head pair: grps {2qp, 2qp+1}
  const int qt = rem & 15;
  const int qh0 = (2 * qp) * 8 + h;   // g adds 8

  const int tid = threadIdx.x;
  const int lane = tid & 63;
  const int w = tid >> 6;
  const int l31 = lane & 31;
  const int hi5 = lane >> 5;
  const int r7 = l31 & 7;

  __shared__ __align__(1024) char sm[2][2][8192];

  const _Float16 QSC = (_Float16)(0.125f * L2E);
  const int qrow0 = b * 2048 + qt * 128 + w * 32 + l31;
  half8 qf[2][4];
  #pragma unroll
  for (int g = 0; g < 2; ++g) {
    const _Float16* qp_ = QKV + (size_t)qrow0 * 3072 + (qh0 + g * 8) * 64 + hi5 * 8;
    #pragma unroll
    for (int s = 0; s < 4; ++s) {
      half8 q = *(const half8*)(qp_ + s * 16);
      #pragma unroll
      for (int e = 0; e < 8; ++e) q[e] = q[e] * QSC;
      qf[g][s] = q;
    }
  }

  const int li = lane >> 3;
  const int lc = lane & 7;
  const int kslot = lc ^ li;
  const int w16li = w * 16 + li;
  const _Float16* Ksrc = QKV + ((size_t)(b * 2048 + w16li)) * 3072 + 2048 + h * 64 + kslot * 8;
  const _Float16* Vsrc = VT + ((size_t)(b * 8 + h) * 64 + w16li) * 2048 + kslot * 8;

  f32x16 oa[2][2];    // [g][i]
  #pragma unroll
  for (int g = 0; g < 2; ++g) {
    oa[g][0] = zero16();
    oa[g][1] = zero16();
  }
  float lreg[2] = {0.f, 0.f};

  {
    char* kd = &sm[0][0][0] + w * 2048;
    char* vd = &sm[0][1][0] + w * 2048;
    gl16(Ksrc, kd);
    gl16(Ksrc + (size_t)8 * 3072, kd + 1024);
    gl16(Vsrc, vd);
    gl16(Vsrc + (size_t)8 * 2048, vd + 1024);
  }
  __syncthreads();

  int cur = 0;
  for (int t = 0; t < 32; ++t) {
    if (t < 31) {
      const int t0 = (t + 1) * 64;
      char* kd = &sm[cur ^ 1][0][0] + w * 2048;
      char* vd = &sm[cur ^ 1][1][0] + w * 2048;
      const _Float16* kg = Ksrc + (size_t)t0 * 3072;
      const _Float16* vg = Vsrc + t0;
      gl16(kg, kd);
      gl16(kg + (size_t)8 * 3072, kd + 1024);
      gl16(vg, vd);
      gl16(vg + (size_t)8 * 2048, vd + 1024);
    }

    const char* Kb = &sm[cur][0][0];
    const char* Vb = &sm[cur][1][0];

    uint32_t pw[2][4][4];       // [g][s][word]
    float ps0 = 0.f, ps1 = 0.f;
    #pragma unroll
    for (int j = 0; j < 2; ++j) {
      const int kr = j * 32 + l31;
      half8 kf[4];
      #pragma unroll
      for (int s = 0; s < 4; ++s)
        kf[s] = *(const half8*)(Kb + kr * 128 + (((2 * s + hi5) ^ r7) << 4));
      #pragma unroll
      for (int g = 0; g < 2; ++g) {
        f32x16 sa = zero16();
        __builtin_amdgcn_s_setprio(1);
        #pragma unroll
        for (int s = 0; s < 4; ++s)
          sa = __builtin_amdgcn_mfma_f32_32x32x16_f16(kf[s], qf[g][s], sa, 0, 0, 0);
        __builtin_amdgcn_s_setprio(0);
        float psl = 0.f;
        #pragma unroll
        for (int r = 0; r < 16; ++r) {
          const float p = __builtin_amdgcn_exp2f(sa[r]);
          sa[r] = p;
          psl += p;
        }
        if (g == 0) ps0 += psl; else ps1 += psl;
        #pragma unroll
        for (int hf = 0; hf < 2; ++hf) {
          const int rb = hf * 8;
          uint32_t w0 = pk2(sa[rb + 0], sa[rb + 1]);
          uint32_t w1 = pk2(sa[rb + 2], sa[rb + 3]);
          uint32_t w2 = pk2(sa[rb + 4], sa[rb + 5]);
          uint32_t w3 = pk2(sa[rb + 6], sa[rb + 7]);
          plswap(w0, w2);
          plswap(w1, w3);
          const int s = 2 * j + hf;
          pw[g][s][0] = w0; pw[g][s][1] = w1; pw[g][s][2] = w2; pw[g][s][3] = w3;
        }
      }
    }
    ps0 += __shfl_xor(ps0, 32);
    ps1 += __shfl_xor(ps1, 32);
    lreg[0] += ps0;
    lreg[1] += ps1;

    // PV: each vf read feeds both heads
    __builtin_amdgcn_s_setprio(1);
    #pragma unroll
    for (int s = 0; s < 4; ++s) {
      union { uint32_t u[4]; half8 h; } p0, p1;
      #pragma unroll
      for (int u = 0; u < 4; ++u) { p0.u[u] = pw[0][s][u]; p1.u[u] = pw[1][s][u]; }
      #pragma unroll
      for (int i = 0; i < 2; ++i) {
        const int vr = i * 32 + l31;
        half8 vf = *(const half8*)(Vb + vr * 128 + (((2 * s + hi5) ^ r7) << 4));
        oa[0][i] = __builtin_amdgcn_mfma_f32_32x32x16_f16(vf, p0.h, oa[0][i], 0, 0, 0);
        oa[1][i] = __builtin_amdgcn_mfma_f32_32x32x16_f16(vf, p1.h, oa[1][i], 0, 0, 0);
      }
    }
    __builtin_amdgcn_s_setprio(0);

    __syncthreads();
    cur ^= 1;
  }

  #pragma unroll
  for (int g = 0; g < 2; ++g) {
    const float inv = 1.0f / lreg[g];
    #pragma unroll
    for (int i = 0; i < 2; ++i) {
      _Float16* dst = AO + (size_t)qrow0 * 2048 + (qh0 + g * 8) * 64 + i * 32 + hi5 * 4;
      #pragma unroll
      for (int q = 0; q < 4; ++q) {
        union { uint32_t u[2]; half4 h4; } o;
        o.u[0] = pk2(oa[g][i][4 * q + 0] * inv, oa[g][i][4 * q + 1] * inv);
        o.u[1] = pk2(oa[g][i][4 * q + 2] * inv, oa[g][i][4 * q + 3] * inv);
        *(half4*)(dst + 8 * q) = o.h4;
      }
    }
  }
}

// ---------------------------------------------------------------------------
extern "C" void kernel_launch(void* const* d_in, const int* in_sizes, int n_in,
                              void* d_out, int out_size, void* d_ws, size_t ws_size,
                              hipStream_t stream) {
  const float* query = (const float*)d_in[0];
  const float* key   = (const float*)d_in[1];
  const float* value = (const float*)d_in[2];
  const float* Wq = (const float*)d_in[3];
  const float* bq = (const float*)d_in[4];
  const float* Wk = (const float*)d_in[5];
  const float* bk = (const float*)d_in[6];
  const float* Wv = (const float*)d_in[7];
  const float* bv = (const float*)d_in[8];
  const float* Wo = (const float*)d_in[9];
  const float* bo = (const float*)d_in[10];
  float* out = (float*)d_out;

  char* ws = (char*)d_ws;
  _Float16* qh    = (_Float16*)(ws);                         // [4096][2048]
  _Float16* kh    = (_Float16*)(ws + 16777216);              // [4096][2048]
  _Float16* vh    = (_Float16*)(ws + 33554432);              // [4096][2048]
  _Float16* WqkvT = (_Float16*)(ws + 50331648);              // [3072][2048]
  _Float16* WoT   = (_Float16*)(ws + 62914560);              // [2048][2048]
  _Float16* QKVh  = (_Float16*)(ws + 71303168);              // [4096][3072]
  _Float16* VT    = (_Float16*)(ws + 96468992);              // [2][8][64][2048]
  _Float16* aoh   = (_Float16*)(ws + 100663296);             // [4096][2048]

  prep_all<<<22528, dim3(32, 8), 0, stream>>>(query, key, value, Wq, Wk, Wv, Wo,
                                              qh, kh, vh, WqkvT, WoT);
  gemm128<0><<<768, 512, 0, stream>>>(qh, kh, vh, WqkvT, bq, bk, bv,
                                      QKVh, nullptr, VT);
  attn_fwd6<<<512, 256, 0, stream>>>(QKVh, VT, aoh);
  gemm128<1><<<512, 512, 0, stream>>>(aoh, nullptr, nullptr, WoT, bo,
                                      nullptr, nullptr, nullptr, out, nullptr);
}

// Round 16
// 232.039 us; speedup vs baseline: 1.0290x; 1.0290x over previous
//
#include <hip/hip_runtime.h>
#include <cstdint>

typedef _Float16 half4 __attribute__((ext_vector_type(4)));
typedef _Float16 half8 __attribute__((ext_vector_type(8)));
typedef _Float16 half16 __attribute__((ext_vector_type(16)));
typedef float f32x4 __attribute__((ext_vector_type(4)));
typedef float f32x16 __attribute__((ext_vector_type(16)));

#define L2E 1.44269504088896340736f

__device__ __forceinline__ void gl16(const void* g, void* l) {
  __builtin_amdgcn_global_load_lds(
      (const __attribute__((address_space(1))) void*)g,
      (__attribute__((address_space(3))) void*)l, 16, 0, 0);
}

__device__ __forceinline__ uint32_t pk2(float a, float b) {
  return __builtin_bit_cast(uint32_t, __builtin_amdgcn_cvt_pkrtz(a, b));
}

__device__ __forceinline__ void plswap(uint32_t& x, uint32_t& y) {
  auto r = __builtin_amdgcn_permlane32_swap((int)x, (int)y, false, false);
  x = (uint32_t)r[0];
  y = (uint32_t)r[1];
}

__device__ __forceinline__ f32x16 zero16() {
  f32x16 z;
  #pragma unroll
  for (int r = 0; r < 16; ++r) z[r] = 0.0f;
  return z;
}

// ---------------------------------------------------------------------------
// Merged prologue: activation fp32->fp16 convert (ids 0..12287) + weight
// transpose/convert (ids 12288..22527). Block (32,8) = 256 threads.
// ---------------------------------------------------------------------------
__global__ __launch_bounds__(256) void prep_all(
    const float* __restrict__ q, const float* __restrict__ k, const float* __restrict__ v,
    const float* __restrict__ Wq, const float* __restrict__ Wk,
    const float* __restrict__ Wv, const float* __restrict__ Wo,
    _Float16* __restrict__ qh, _Float16* __restrict__ kh, _Float16* __restrict__ vh,
    _Float16* __restrict__ WqkvT, _Float16* __restrict__ WoT)
{
  int id = blockIdx.x;
  const int tid = threadIdx.y * 32 + threadIdx.x;
  if (id < 12288) {
    const int z = id >> 12;
    const int x = id & 4095;
    const float* src = (z == 0) ? q : (z == 1 ? k : v);
    _Float16* dst    = (z == 0) ? qh : (z == 1 ? kh : vh);
    size_t i = ((size_t)x * 256 + tid) * 8;
    float4 a = *(const float4*)(src + i);
    float4 b = *(const float4*)(src + i + 4);
    half8 o;
    o[0] = (_Float16)a.x; o[1] = (_Float16)a.y; o[2] = (_Float16)a.z; o[3] = (_Float16)a.w;
    o[4] = (_Float16)b.x; o[5] = (_Float16)b.y; o[6] = (_Float16)b.z; o[7] = (_Float16)b.w;
    *(half8*)(dst + i) = o;
    return;
  }
  id -= 12288;
  const float* src;
  _Float16* dst;
  int N, tx, ty;
  if (id < 4096)      { src = Wq; dst = WqkvT;                        N = 2048; tx = id & 63; ty = id >> 6; }
  else if (id < 5120) { id -= 4096; src = Wk; dst = WqkvT + (size_t)2048 * 2048; N = 512; tx = id & 15; ty = id >> 4; }
  else if (id < 6144) { id -= 5120; src = Wv; dst = WqkvT + (size_t)2560 * 2048; N = 512; tx = id & 15; ty = id >> 4; }
  else                { id -= 6144; src = Wo; dst = WoT;              N = 2048; tx = id & 63; ty = id >> 6; }
  const int n0 = tx * 32, k0 = ty * 32;
  __shared__ float t[32][33];
  #pragma unroll
  for (int i = 0; i < 4; ++i)
    t[threadIdx.y + i * 8][threadIdx.x] =
        src[(size_t)(k0 + threadIdx.y + i * 8) * N + n0 + threadIdx.x];
  __syncthreads();
  #pragma unroll
  for (int i = 0; i < 4; ++i)
    dst[(size_t)(n0 + threadIdx.y + i * 8) * 2048 + k0 + threadIdx.x] =
        (_Float16)t[threadIdx.x][threadIdx.y + i * 8];
}

// ---------------------------------------------------------------------------
// fp16 GEMM v9 (R14-proven, unchanged): BM=128, BN=128, BK=32, 512 thr /
// 8 waves, all-gl16 staging, 3-buffer LDS, counted vmcnt(2), raw s_barrier,
// XCD swizzle. MODE 0: QKV proj (grid 768), fused V^T epilogue.
// MODE 1: O proj (grid 512), fp32 out.
// ---------------------------------------------------------------------------
template<int MODE>
__global__ __launch_bounds__(512, 2) void gemm128(
    const _Float16* __restrict__ Aq, const _Float16* __restrict__ Ak, const _Float16* __restrict__ Av,
    const _Float16* __restrict__ Bt,
    const float* __restrict__ bias0, const float* __restrict__ bias1, const float* __restrict__ bias2,
    _Float16* __restrict__ Ch, float* __restrict__ Cf, _Float16* __restrict__ VTo)
{
  constexpr int K = 2048;
  constexpr int N = (MODE == 0) ? 3072 : 2048;
  constexpr int NB = N / 128;
  constexpr int G = 32 * NB;
  constexpr int BUF = 8192 + 8192;
  constexpr int TPAD = 136;

  const int wg = blockIdx.x;
  const int work = (wg & 7) * (G / 8) + (wg >> 3);
  const int m0 = (work / NB) * 128;
  const int n0 = (work % NB) * 128;

  const _Float16* A = Aq;
  if constexpr (MODE == 0) { if (n0 >= 2560) A = Av; else if (n0 >= 2048) A = Ak; }

  const int tid = threadIdx.x;
  const int lane = tid & 63;
  const int w = tid >> 6;
  const int wr = w >> 2;
  const int wc = w & 3;
  const int lo = lane & 15, hi = lane >> 4;

  __shared__ __align__(1024) char smem[3 * BUF];

  f32x4 acc[4][2];
  #pragma unroll
  for (int mt = 0; mt < 4; ++mt)
    #pragma unroll
    for (int nt = 0; nt < 2; ++nt)
      acc[mt][nt] = (f32x4){0.f, 0.f, 0.f, 0.f};

  const _Float16* pB = Bt + (size_t)(n0 + w * 16 + (lane >> 2)) * K + (lane & 3) * 8;
  const _Float16* pA = A  + (size_t)(m0 + w * 16 + (lane >> 2)) * K + (lane & 3) * 8;
  const int dstB = 8192 + w * 1024;
  const int dstA = w * 1024;

  #define STAGE(base)                                                         \
    do {                                                                      \
      gl16(pA, (base) + dstA);                                                \
      gl16(pB, (base) + dstB);                                                \
    } while (0)

  STAGE(smem);
  pA += 32; pB += 32;
  STAGE(smem + BUF);
  pA += 32; pB += 32;
  asm volatile("s_waitcnt vmcnt(2)" ::: "memory");
  __builtin_amdgcn_s_barrier();

  const int abase = (wr * 64 + lo) * 64 + hi * 16;
  const int bbase = 8192 + (wc * 32 + lo) * 64 + hi * 16;

  int c = 0;
  for (int t = 0; t < 64; ++t) {
    int c1 = c + 1; if (c1 == 3) c1 = 0;
    int c2 = c1 + 1; if (c2 == 3) c2 = 0;
    if (t < 62) {
      STAGE(smem + c2 * BUF);
      pA += 32; pB += 32;
    }

    const char* bc = smem + c * BUF;
    half8 af[4], bf[2];
    #pragma unroll
    for (int mt = 0; mt < 4; ++mt) af[mt] = *(const half8*)(bc + abase + mt * 1024);
    #pragma unroll
    for (int nt = 0; nt < 2; ++nt) bf[nt] = *(const half8*)(bc + bbase + nt * 1024);

    __builtin_amdgcn_s_setprio(1);
    #pragma unroll
    for (int mt = 0; mt < 4; ++mt)
      #pragma unroll
      for (int nt = 0; nt < 2; ++nt)
        acc[mt][nt] = __builtin_amdgcn_mfma_f32_16x16x32_f16(af[mt], bf[nt], acc[mt][nt], 0, 0, 0);
    __builtin_amdgcn_s_setprio(0);

    if (t < 62)       asm volatile("s_waitcnt vmcnt(2)" ::: "memory");
    else if (t == 62) asm volatile("s_waitcnt vmcnt(0)" ::: "memory");
    if (t < 63) __builtin_amdgcn_s_barrier();
    c = c1;
  }
  #undef STAGE

  const bool isV = (MODE == 0) && (n0 >= 2560);
  float* T = (float*)smem;
  const int tr = tid >> 4;
  const int sc = tid & 15;
  #pragma unroll
  for (int mp = 0; mp < 4; ++mp) {
    __syncthreads();
    #pragma unroll
    for (int nt = 0; nt < 2; ++nt)
      #pragma unroll
      for (int r = 0; r < 4; ++r)
        T[(wr * 16 + 4 * hi + r) * TPAD + wc * 32 + nt * 16 + lo] = acc[mp][nt][r];
    __syncthreads();
    if (isV) {
      const int cv = tid & 127;
      const int tg = tid >> 7;
      const int run = tg >> 1, hb = tg & 1;
      const int vd = n0 - 2560 + cv;
      const int hV = vd >> 6, dV = vd & 63;
      const float bias = bias2[vd];
      const int trow0 = run * 16 + hb * 8;
      const int tglob = m0 + run * 64 + mp * 16 + hb * 8;
      const int bb = tglob >> 11;
      const int tloc = tglob & 2047;
      half8 o;
      #pragma unroll
      for (int e = 0; e < 8; ++e)
        o[e] = (_Float16)(T[(trow0 + e) * TPAD + cv] + bias);
      *(half8*)(VTo + ((size_t)(bb * 8 + hV) * 64 + dV) * 2048 + tloc) = o;
    } else {
      const int grow = m0 + (tr >> 4) * 64 + mp * 16 + (tr & 15);
      const int gcol = n0 + sc * 8;
      const float* Trow = T + tr * TPAD + sc * 8;
      const float* bp = bias0;
      int cb = gcol;
      if constexpr (MODE == 0) {
        if (gcol >= 2048) { bp = bias1; cb = gcol - 2048; }
      }
      float4 v0 = ((const float4*)Trow)[0];
      float4 v1 = ((const float4*)Trow)[1];
      float4 b0 = ((const float4*)(bp + cb))[0];
      float4 b1 = ((const float4*)(bp + cb))[1];
      if constexpr (MODE == 0) {
        half8 o;
        o[0] = (_Float16)(v0.x + b0.x); o[1] = (_Float16)(v0.y + b0.y);
        o[2] = (_Float16)(v0.z + b0.z); o[3] = (_Float16)(v0.w + b0.w);
        o[4] = (_Float16)(v1.x + b1.x); o[5] = (_Float16)(v1.y + b1.y);
        o[6] = (_Float16)(v1.z + b1.z); o[7] = (_Float16)(v1.w + b1.w);
        *(half8*)(Ch + (size_t)grow * N + gcol) = o;
      } else {
        float* dstp = Cf + (size_t)grow * N + gcol;
        float4 o0 = {v0.x + b0.x, v0.y + b0.y, v0.z + b0.z, v0.w + b0.w};
        float4 o1 = {v1.x + b1.x, v1.y + b1.y, v1.z + b1.z, v1.w + b1.w};
        ((float4*)dstp)[0] = o0;
        ((float4*)dstp)[1] = o1;
      }
    }
  }
}

// ---------------------------------------------------------------------------
// Flash attention v4 — EXACT R6/R13/R14-measured optimum (86.5 us): no-max
// softmax, exp2-domain Q prescale, qb=1 / 1024 blocks, 2-buffer gl16 KV
// staging, __syncthreads per tile, __launch_bounds__(256, 4).
// (Session evidence: (256,5) +7us, 3-buffer counted-vmcnt +8us, GQA
// 2-head-ILP +2us — all perturbations regress. This config is the optimum.)
// ---------------------------------------------------------------------------
__global__ __launch_bounds__(256, 4) void attn_fwd4(
    const _Float16* __restrict__ QKV, const _Float16* __restrict__ VT,
    _Float16* __restrict__ AO)
{
  const int wg = blockIdx.x;
  const int work = (wg & 7) * 128 + (wg >> 3);
  const int bh = work >> 6;
  const int b = bh >> 3, h = bh & 7;
  const int rem = work & 63;
  const int qh = (rem >> 4) * 8 + h;
  const int qt = rem & 15;

  const int tid = threadIdx.x;
  const int lane = tid & 63;
  const int w = tid >> 6;
  const int l31 = lane & 31;
  const int hi5 = lane >> 5;
  const int r7 = l31 & 7;

  __shared__ __align__(1024) char sm[2][2][8192];

  const _Float16 QSC = (_Float16)(0.125f * L2E);
  const int qrow0 = b * 2048 + qt * 128 + w * 32 + l31;
  half8 qf[4];
  {
    const _Float16* qp = QKV + (size_t)qrow0 * 3072 + qh * 64 + hi5 * 8;
    #pragma unroll
    for (int s = 0; s < 4; ++s) {
      half8 q = *(const half8*)(qp + s * 16);
      #pragma unroll
      for (int e = 0; e < 8; ++e) q[e] = q[e] * QSC;
      qf[s] = q;
    }
  }

  const int li = lane >> 3;
  const int lc = lane & 7;
  const int kslot = lc ^ li;
  const int w16li = w * 16 + li;
  const _Float16* Ksrc = QKV + ((size_t)(b * 2048 + w16li)) * 3072 + 2048 + h * 64 + kslot * 8;
  const _Float16* Vsrc = VT + ((size_t)(b * 8 + h) * 64 + w16li) * 2048 + kslot * 8;

  f32x16 oa[2];
  oa[0] = zero16();
  oa[1] = zero16();
  float lreg = 0.f;

  {
    char* kd = &sm[0][0][0] + w * 2048;
    char* vd = &sm[0][1][0] + w * 2048;
    gl16(Ksrc, kd);
    gl16(Ksrc + (size_t)8 * 3072, kd + 1024);
    gl16(Vsrc, vd);
    gl16(Vsrc + (size_t)8 * 2048, vd + 1024);
  }
  __syncthreads();

  int cur = 0;
  for (int t = 0; t < 32; ++t) {
    if (t < 31) {
      const int t0 = (t + 1) * 64;
      char* kd = &sm[cur ^ 1][0][0] + w * 2048;
      char* vd = &sm[cur ^ 1][1][0] + w * 2048;
      const _Float16* kg = Ksrc + (size_t)t0 * 3072;
      const _Float16* vg = Vsrc + t0;
      gl16(kg, kd);
      gl16(kg + (size_t)8 * 3072, kd + 1024);
      gl16(vg, vd);
      gl16(vg + (size_t)8 * 2048, vd + 1024);
    }

    const char* Kb = &sm[cur][0][0];
    const char* Vb = &sm[cur][1][0];

    uint32_t pw[4][4];
    float ps = 0.f;
    #pragma unroll
    for (int j = 0; j < 2; ++j) {
      f32x16 sa = zero16();
      const int kr = j * 32 + l31;
      __builtin_amdgcn_s_setprio(1);
      #pragma unroll
      for (int s = 0; s < 4; ++s) {
        half8 kf = *(const half8*)(Kb + kr * 128 + (((2 * s + hi5) ^ r7) << 4));
        sa = __builtin_amdgcn_mfma_f32_32x32x16_f16(kf, qf[s], sa, 0, 0, 0);
      }
      __builtin_amdgcn_s_setprio(0);
      #pragma unroll
      for (int r = 0; r < 16; ++r) {
        const float p = __builtin_amdgcn_exp2f(sa[r]);
        sa[r] = p;
        ps += p;
      }
      #pragma unroll
      for (int hf = 0; hf < 2; ++hf) {
        const int rb = hf * 8;
        uint32_t w0 = pk2(sa[rb + 0], sa[rb + 1]);
        uint32_t w1 = pk2(sa[rb + 2], sa[rb + 3]);
        uint32_t w2 = pk2(sa[rb + 4], sa[rb + 5]);
        uint32_t w3 = pk2(sa[rb + 6], sa[rb + 7]);
        plswap(w0, w2);
        plswap(w1, w3);
        const int s = 2 * j + hf;
        pw[s][0] = w0; pw[s][1] = w1; pw[s][2] = w2; pw[s][3] = w3;
      }
    }
    ps += __shfl_xor(ps, 32);
    lreg += ps;

    __builtin_amdgcn_s_setprio(1);
    #pragma unroll
    for (int s = 0; s < 4; ++s) {
      union { uint32_t u[4]; half8 h; } p0;
      #pragma unroll
      for (int u = 0; u < 4; ++u) p0.u[u] = pw[s][u];
      #pragma unroll
      for (int i = 0; i < 2; ++i) {
        const int vr = i * 32 + l31;
        half8 vf = *(const half8*)(Vb + vr * 128 + (((2 * s + hi5) ^ r7) << 4));
        oa[i] = __builtin_amdgcn_mfma_f32_32x32x16_f16(vf, p0.h, oa[i], 0, 0, 0);
      }
    }
    __builtin_amdgcn_s_setprio(0);

    __syncthreads();
    cur ^= 1;
  }

  {
    const float inv = 1.0f / lreg;
    #pragma unroll
    for (int i = 0; i < 2; ++i) {
      _Float16* dst = AO + (size_t)qrow0 * 2048 + qh * 64 + i * 32 + hi5 * 4;
      #pragma unroll
      for (int q = 0; q < 4; ++q) {
        union { uint32_t u[2]; half4 h4; } o;
        o.u[0] = pk2(oa[i][4 * q + 0] * inv, oa[i][4 * q + 1] * inv);
        o.u[1] = pk2(oa[i][4 * q + 2] * inv, oa[i][4 * q + 3] * inv);
        *(half4*)(dst + 8 * q) = o.h4;
      }
    }
  }
}

// ---------------------------------------------------------------------------
extern "C" void kernel_launch(void* const* d_in, const int* in_sizes, int n_in,
                              void* d_out, int out_size, void* d_ws, size_t ws_size,
                              hipStream_t stream) {
  const float* query = (const float*)d_in[0];
  const float* key   = (const float*)d_in[1];
  const float* value = (const float*)d_in[2];
  const float* Wq = (const float*)d_in[3];
  const float* bq = (const float*)d_in[4];
  const float* Wk = (const float*)d_in[5];
  const float* bk = (const float*)d_in[6];
  const float* Wv = (const float*)d_in[7];
  const float* bv = (const float*)d_in[8];
  const float* Wo = (const float*)d_in[9];
  const float* bo = (const float*)d_in[10];
  float* out = (float*)d_out;

  char* ws = (char*)d_ws;
  _Float16* qh    = (_Float16*)(ws);                         // [4096][2048]
  _Float16* kh    = (_Float16*)(ws + 16777216);              // [4096][2048]
  _Float16* vh    = (_Float16*)(ws + 33554432);              // [4096][2048]
  _Float16* WqkvT = (_Float16*)(ws + 50331648);              // [3072][2048]
  _Float16* WoT   = (_Float16*)(ws + 62914560);              // [2048][2048]
  _Float16* QKVh  = (_Float16*)(ws + 71303168);              // [4096][3072]
  _Float16* VT    = (_Float16*)(ws + 96468992);              // [2][8][64][2048]
  _Float16* aoh   = (_Float16*)(ws + 100663296);             // [4096][2048]

  prep_all<<<22528, dim3(32, 8), 0, stream>>>(query, key, value, Wq, Wk, Wv, Wo,
                                              qh, kh, vh, WqkvT, WoT);
  gemm128<0><<<768, 512, 0, stream>>>(qh, kh, vh, WqkvT, bq, bk, bv,
                                      QKVh, nullptr, VT);
  attn_fwd4<<<1024, 256, 0, stream>>>(QKVh, VT, aoh);
  gemm128<1><<<512, 512, 0, stream>>>(aoh, nullptr, nullptr, WoT, bo,
                                      nullptr, nullptr, nullptr, out, nullptr);
}